// Round 6
// baseline (128.606 us; speedup 1.0000x reference)
//
#include <hip/hip_runtime.h>
#include <hip/hip_bf16.h>
#include <math.h>

#define B 16
#define C 512
#define CQ 256
#define N 1024

typedef short bf16x8 __attribute__((ext_vector_type(8)));
typedef _Float16 f16x8 __attribute__((ext_vector_type(8)));
typedef float f32x4 __attribute__((ext_vector_type(4)));
typedef unsigned short ushort;
typedef ushort u16x4 __attribute__((ext_vector_type(4)));

__device__ __forceinline__ ushort f2h(float f) {
    _Float16 h = (_Float16)f;
    return *(ushort*)&h;
}
__device__ __forceinline__ f16x8 as_h(bf16x8 v) {
    union { bf16x8 s; f16x8 h; } u; u.s = v; return u.h;
}

__device__ __forceinline__ void gload16(void* lds, const void* g) {
    __builtin_amdgcn_global_load_lds(
        (const __attribute__((address_space(1))) void*)g,
        (__attribute__((address_space(3))) void*)lds, 16, 0, 0);
}

__device__ __forceinline__ void barrier_lgkm() {
    asm volatile("s_waitcnt lgkmcnt(0)" ::: "memory");
    __builtin_amdgcn_s_barrier();
    __builtin_amdgcn_sched_barrier(0);
}

// ---------------------------------------------------------------------------
// Merged projection GEMMs, ONE dispatch, XCD mapping PRESERVED.
// Round-4's merge failed because half-select consumed bit 0 (hardware XCD =
// lin & 7). Here: xcd = lin&7 FIRST, then half = (lin>>3)&1, slot = lin>>4 —
// per-half mapping is bit-identical to the two separate dispatches.
// half 0: qkT[b][n][col] = xT[b] . [Wq;Wk]^T + bqk[col]   (grid-part 4x8)
// half 1: v  [b][c][n]   = Wv . xT[b]^T      + bv[row]    (grid-part 8x4)
// Body = proven gemm128s (BK=128, XOR-swizzled LDS, fp16 MFMA, fp16 out).
// ---------------------------------------------------------------------------
__global__ __launch_bounds__(256) void gemm_merged(
    const ushort* __restrict__ xT, const ushort* __restrict__ Wqk,
    const ushort* __restrict__ Wv16,
    ushort* __restrict__ qkT, ushort* __restrict__ v_,
    const float* __restrict__ bqk, const float* __restrict__ bv)
{
    __shared__ __align__(16) ushort As[128 * 128];   // 32 KB
    __shared__ __align__(16) ushort Bs[128 * 128];   // 32 KB

    const int lin  = blockIdx.x;          // 0..1023
    const int xcd  = lin & 7;             // hardware XCD (preserved!)
    const int half = (lin >> 3) & 1;      // which GEMM
    const int slot = lin >> 4;            // 0..63
    const int bz   = xcd + 8 * (slot >> 5);
    const int wxy  = slot & 31;

    int bx, by;
    const ushort* A;  long long sA;
    const ushort* BT; long long sB;
    ushort* Ch;       long long sC;
    const float* bias; int bias_mode; int Ncols;
    if (half == 0) {
        bx = wxy & 3; by = wxy >> 2;
        A = xT;   sA = (long long)N * C;  BT = Wqk;  sB = 0;
        Ch = qkT; sC = (long long)N * 512;
        bias = bqk; bias_mode = 2; Ncols = 512;
    } else {
        bx = wxy & 7; by = wxy >> 3;
        A = Wv16; sA = 0;                 BT = xT;   sB = (long long)N * C;
        Ch = v_;  sC = (long long)C * N;
        bias = bv;  bias_mode = 1; Ncols = N;
    }
    const int K = C;                      // 512 for both

    const int tid  = threadIdx.x;
    const int lane = tid & 63;
    const int w    = tid >> 6;
    const int wr   = (w >> 1) * 64;
    const int wc   = (w & 1) * 64;
    const int fr   = lane & 15;
    const int ko2  = (lane >> 4) * 16;    // byte offset of lane's K-octet

    const int brow = by * 128;
    const int bcol = bx * 128;
    const size_t K2 = (size_t)K * 2;

    const char* Ab = (const char*)(A  + (size_t)bz * sA + (size_t)brow * K);
    const char* Bb = (const char*)(BT + (size_t)bz * sB + (size_t)bcol * K);

    const int sr = tid >> 4;              // staging row base 0..15
    const int ss = (tid & 15) * 16;       // byte seg within 256B row

    f32x4 acc[4][4] = {};

    for (int k0 = 0; k0 < K; k0 += 128) {
#pragma unroll
        for (int p = 0; p < 8; ++p) {
            const int row = p * 16 + sr;
            const size_t so = (size_t)row * K2 + (size_t)k0 * 2
                            + (size_t)(ss ^ ((row & 15) << 4));
            gload16((char*)As + p * 4096 + tid * 16, Ab + so);
            gload16((char*)Bs + p * 4096 + tid * 16, Bb + so);
        }
        __syncthreads();
#pragma unroll
        for (int k32 = 0; k32 < 4; ++k32) {
            const int kswz = (k32 * 64 + ko2) ^ (fr << 4);
            bf16x8 ah[4], bh[4];
#pragma unroll
            for (int m = 0; m < 4; ++m)
                ah[m] = *(const bf16x8*)((const char*)As + (wr + m * 16 + fr) * 256 + kswz);
#pragma unroll
            for (int n = 0; n < 4; ++n)
                bh[n] = *(const bf16x8*)((const char*)Bs + (wc + n * 16 + fr) * 256 + kswz);
#pragma unroll
            for (int m = 0; m < 4; ++m)
#pragma unroll
                for (int n = 0; n < 4; ++n)
                    acc[m][n] = __builtin_amdgcn_mfma_f32_16x16x32_f16(
                        as_h(ah[m]), as_h(bh[n]), acc[m][n], 0, 0, 0);
        }
        __syncthreads();
    }

    // Epilogue: C/D layout col = lane&15, row = (lane>>4)*4 + r; fp16 store
    const int crow = brow + wr + (lane >> 4) * 4;
    const int ccol = bcol + wc + fr;
    const size_t cbase = (size_t)bz * sC;
#pragma unroll
    for (int m = 0; m < 4; ++m) {
#pragma unroll
        for (int n = 0; n < 4; ++n) {
            const float cb = (bias_mode == 2) ? bias[ccol + n * 16] : 0.f;
#pragma unroll
            for (int r = 0; r < 4; ++r) {
                const int row = crow + m * 16 + r;
                const int col = ccol + n * 16;
                float vv = acc[m][n][r] + ((bias_mode == 1) ? bias[row] : cb);
                Ch[cbase + (size_t)row * Ncols + col] = f2h(vv);
            }
        }
    }
}

// ---------------------------------------------------------------------------
// Fully fused attention — round-0 structure (fused epilogue; r5 proved the
// split epilogue is a net loss: only 6 us marginal in-kernel vs ~18 us as a
// separate pass) with ONE change: the PV loop's vmcnt(0)-drain-per-tile is
// replaced by a COUNTED-vmcnt depth-2 pipeline (the QK phase's proven
// pattern):
//   KVBLK 64 -> 32; 4 V-buffers x 32 KB + 4 P-buffers x 4608 B = 149504 B
//   (exactly the existing LDS array). Per step s (0..31):
//     { stageV(s+2) [4 loads/thr]; repackP(s+2);
//       vmcnt(8) lgkmcnt(0); barrier; 16 MFMA on V(s),P(s) }
//   Buffer (s+2)&3 was last read at iter s-2 => >=2 barriers separate
//   write from read. j-accumulation order into apv is unchanged =>
//   bitwise-identical output.
// acc[jidx] holds S[i][j], j = (jidx>>1)*128 + (jidx&1)*64 + wg4*16 + fr;
// step s covers j in [32s,32s+32) => jidx = s>>1, participating waves
// (wg4>>1)==(s&1), in-tile col = (wg4&1)*16 + fr.
// ---------------------------------------------------------------------------
__global__ __launch_bounds__(512, 2) void fused_attn(
    const ushort* __restrict__ qk, const ushort* __restrict__ vmat,
    const float* __restrict__ Wa, const float* __restrict__ ba,
    const float* __restrict__ gamma, const float* __restrict__ x,
    float* __restrict__ dout)
{
    __shared__ __align__(16) char lds[149504];
    __shared__ float redbuf[2][2][4][32];
    __shared__ float redA[8][64];
    __shared__ float agL[64];

    const int tid  = threadIdx.x;
    const int lane = tid & 63;
    const int w    = tid >> 6;           // 0..7
    const int g    = w >> 2;             // QK row group 0/1
    const int wg4  = w & 3;              // QK col-wave within group
    const int fr   = lane & 15;
    const int il0  = (lane >> 4) * 4;
    const int ko2  = (lane >> 4) * 16;   // byte offset of lane's K-octet

    // XCD-aware bijective remap (256 wgs, 8 XCDs => 2 batches/XCD)
    const int wgid = blockIdx.x + gridDim.x * blockIdx.y;
    const int nid  = (wgid & 7) * 32 + (wgid >> 3);
    const int b    = nid >> 4;
    const int i0   = (nid & 15) * 64;

    const char* qkB = (const char*)qk + (size_t)b * N * 1024;
    const char* vB  = (const char*)vmat + (size_t)b * C * N * 2;

    const int srow = tid >> 4;          // 0..31
    const int ssg  = (tid & 15) * 16;   // byte seg in 256B row

    // ---- hoist q fragments for BOTH K-halves (global -> VGPR) ----
    f16x8 a_h[2][2][4];
#pragma unroll
    for (int ks0 = 0; ks0 < 2; ++ks0)
#pragma unroll
        for (int m = 0; m < 2; ++m) {
            const char* qr = qkB + (size_t)(i0 + g * 32 + m * 16 + fr) * 1024
                           + ks0 * 256 + (lane >> 4) * 16;
#pragma unroll
            for (int k32 = 0; k32 < 4; ++k32)
                a_h[ks0][m][k32] = *(const f16x8*)(qr + k32 * 64);
        }

    // ---- QK staging: 4 buffers of 32 KB ----
    auto stageK = [&](int s) {
        const int jt_  = s & 7;
        const int ks0_ = s >> 3;
        char* dst = lds + (s & 3) * 32768;
#pragma unroll
        for (int p = 0; p < 4; ++p) {
            const int row = p * 32 + srow;
            const size_t so = (size_t)(jt_ * 128 + row) * 1024 + 512
                            + (size_t)(ks0_ * 256)
                            + (size_t)(ssg ^ ((row & 15) << 4));
            gload16(dst + p * 8192 + tid * 16, qkB + so);
        }
    };

    f32x4 acc[16][2];
#pragma unroll
    for (int jt = 0; jt < 16; ++jt)
#pragma unroll
        for (int m = 0; m < 2; ++m)
            acc[jt][m] = (f32x4){0.f, 0.f, 0.f, 0.f};

    stageK(0);
    stageK(1);

#pragma unroll
    for (int s = 0; s < 16; ++s) {
        if (s + 2 < 16) stageK(s + 2);
        if (s < 14)       asm volatile("s_waitcnt vmcnt(8)" ::: "memory");
        else if (s == 14) asm volatile("s_waitcnt vmcnt(4)" ::: "memory");
        else              asm volatile("s_waitcnt vmcnt(0)" ::: "memory");
        __builtin_amdgcn_s_barrier();
        __builtin_amdgcn_sched_barrier(0);
        const char* kb = lds + (s & 3) * 32768;
        const int ks0 = s >> 3;
#pragma unroll
        for (int sub = 0; sub < 2; ++sub) {
            const int jrow = sub * 64 + wg4 * 16 + fr;   // 0..127
            const int rb   = jrow * 256;
            const int jidx = (s & 7) * 2 + sub;
#pragma unroll
            for (int k32 = 0; k32 < 4; ++k32) {
                const int kswz = (k32 * 64 + ko2) ^ (fr << 4);
                f16x8 b_h = *(const f16x8*)(kb + rb + kswz);
#pragma unroll
                for (int m = 0; m < 2; ++m)
                    acc[jidx][m] = __builtin_amdgcn_mfma_f32_16x16x32_f16(
                        a_h[ks0][m][k32], b_h, acc[jidx][m], 0, 0, 0);
            }
        }
    }

    // ---- V staging: 4 buffers of 32 KB (V[512 c][32 j], 64 B rows) ----
    auto stageV32 = [&](int s) {
        char* dst = lds + (s & 3) * 32768;
#pragma unroll
        for (int p = 0; p < 4; ++p) {
            const int ch  = p * 512 + tid;
            const int row = ch >> 2;          // 0..511 (channel)
            const int sg  = (ch & 3) * 16;    // 16B seg in 64B row
            const size_t so = (size_t)row * (N * 2) + (size_t)(s * 64)
                            + (size_t)(sg ^ ((row & 3) << 4));
            gload16(dst + ch * 16, vB + so);
        }
    };
    stageV32(0);                          // in flight under softmax
    stageV32(1);

    // ---- row max (lgkm-only barriers; vmcnt untouched) ----
    float mx[2][4];
#pragma unroll
    for (int m = 0; m < 2; ++m)
#pragma unroll
        for (int r = 0; r < 4; ++r) {
            float v = acc[0][m][r];
#pragma unroll
            for (int jt = 1; jt < 16; ++jt) v = fmaxf(v, acc[jt][m][r]);
            mx[m][r] = v;
        }
#pragma unroll
    for (int off = 1; off < 16; off <<= 1)
#pragma unroll
        for (int m = 0; m < 2; ++m)
#pragma unroll
            for (int r = 0; r < 4; ++r)
                mx[m][r] = fmaxf(mx[m][r], __shfl_xor(mx[m][r], off, 64));
    if (fr == 0) {
#pragma unroll
        for (int m = 0; m < 2; ++m)
#pragma unroll
            for (int r = 0; r < 4; ++r)
                redbuf[0][g][wg4][m * 16 + il0 + r] = mx[m][r];
    }
    barrier_lgkm();
#pragma unroll
    for (int m = 0; m < 2; ++m)
#pragma unroll
        for (int r = 0; r < 4; ++r) {
            const int row = m * 16 + il0 + r;
            mx[m][r] = fmaxf(fmaxf(redbuf[0][g][0][row], redbuf[0][g][1][row]),
                             fmaxf(redbuf[0][g][2][row], redbuf[0][g][3][row]));
        }

    // ---- exp + row sum ----
    float sm[2][4] = {};
#pragma unroll
    for (int jt = 0; jt < 16; ++jt)
#pragma unroll
        for (int m = 0; m < 2; ++m) {
            f32x4 e;
#pragma unroll
            for (int r = 0; r < 4; ++r) {
                e[r] = __expf(acc[jt][m][r] - mx[m][r]);
                sm[m][r] += e[r];
            }
            acc[jt][m] = e;
        }
#pragma unroll
    for (int off = 1; off < 16; off <<= 1)
#pragma unroll
        for (int m = 0; m < 2; ++m)
#pragma unroll
            for (int r = 0; r < 4; ++r)
                sm[m][r] += __shfl_xor(sm[m][r], off, 64);
    if (fr == 0) {
#pragma unroll
        for (int m = 0; m < 2; ++m)
#pragma unroll
            for (int r = 0; r < 4; ++r)
                redbuf[1][g][wg4][m * 16 + il0 + r] = sm[m][r];
    }
    barrier_lgkm();
#pragma unroll
    for (int m = 0; m < 2; ++m)
#pragma unroll
        for (int r = 0; r < 4; ++r) {
            const int row = m * 16 + il0 + r;
            float s = redbuf[1][g][0][row] + redbuf[1][g][1][row]
                    + redbuf[1][g][2][row] + redbuf[1][g][3][row];
            mx[m][r] = 1.f / s;        // reuse mx as inv-sum
        }

    // ---- PV phase: counted-vmcnt depth-2 pipeline over 32 steps ----
    char* pPb = lds + 131072;            // 4 P buffers x 4608 B
    f32x4 apv[4][4] = {};                // [c-frag][i-frag]

    auto repackP = [&](int s) {
        if ((wg4 >> 1) == (s & 1)) {     // wave-uniform branch
            ushort* pS = (ushort*)(pPb + (s & 3) * 4608);
            const int jidx = s >> 1;
            const int colj = (wg4 & 1) * 16 + fr;
#pragma unroll
            for (int m = 0; m < 2; ++m) {
                const int lr = g * 32 + m * 16 + il0;
#pragma unroll
                for (int r = 0; r < 4; ++r)
                    pS[(lr + r) * 36 + colj] = f2h(acc[jidx][m][r] * mx[m][r]);
            }
        }
    };
    repackP(0);
    repackP(1);

#pragma unroll
    for (int s = 0; s < 32; ++s) {
        if (s + 2 < 32) {
            stageV32(s + 2);             // issue early (overlaps 2 MFMA phases)
            repackP(s + 2);              // LDS write, buffer (s+2)&3
        }
        if (s < 30)       asm volatile("s_waitcnt vmcnt(8) lgkmcnt(0)" ::: "memory");
        else if (s == 30) asm volatile("s_waitcnt vmcnt(4) lgkmcnt(0)" ::: "memory");
        else              asm volatile("s_waitcnt vmcnt(0) lgkmcnt(0)" ::: "memory");
        __builtin_amdgcn_s_barrier();
        __builtin_amdgcn_sched_barrier(0);
        const char* vb = lds + (s & 3) * 32768;
        const char* pS = pPb + (s & 3) * 4608;
        f16x8 af[4], bf[4];
#pragma unroll
        for (int cf = 0; cf < 4; ++cf) {
            const int row = w * 64 + cf * 16 + fr;
            af[cf] = *(const f16x8*)(vb + row * 64 + (ko2 ^ ((row & 3) << 4)));
        }
#pragma unroll
        for (int f = 0; f < 4; ++f)
            bf[f] = *(const f16x8*)(pS + (f * 16 + fr) * 72 + ko2);
#pragma unroll
        for (int cf = 0; cf < 4; ++cf)
#pragma unroll
            for (int f = 0; f < 4; ++f)
                apv[cf][f] = __builtin_amdgcn_mfma_f32_16x16x32_f16(
                    af[cf], bf[f], apv[cf][f], 0, 0, 0);
    }

    // ---- gate ----
    float pg[4] = {0.f, 0.f, 0.f, 0.f};
#pragma unroll
    for (int cf = 0; cf < 4; ++cf)
#pragma unroll
        for (int r = 0; r < 4; ++r) {
            const float wv = Wa[w * 64 + cf * 16 + il0 + r];
#pragma unroll
            for (int f = 0; f < 4; ++f)
                pg[f] += wv * apv[cf][f][r];
        }
#pragma unroll
    for (int off = 16; off < 64; off <<= 1)
#pragma unroll
        for (int f = 0; f < 4; ++f)
            pg[f] += __shfl_xor(pg[f], off, 64);
    if (lane < 16) {
#pragma unroll
        for (int f = 0; f < 4; ++f)
            redA[w][f * 16 + fr] = pg[f];
    }
    barrier_lgkm();                      // V reads consumed; redA visible
    if (tid < 64) {
        float s = ba[0];
#pragma unroll
        for (int k = 0; k < 8; ++k) s += redA[k][tid];
        agL[tid] = 1.f / (1.f + __expf(-s));
    }

    // ---- final epilogue: per i-half, fp32 repack (pad 33 dwords) + store ----
    const size_t BCN = (size_t)B * C * N;
    const float gmm = gamma[0];
    float* oS = (float*)lds;             // 512 rows x 33 f32 = 67584 B

#pragma unroll
    for (int h = 0; h < 2; ++h) {
#pragma unroll
        for (int cf = 0; cf < 4; ++cf) {
            const int crow = w * 64 + cf * 16 + il0;
#pragma unroll
            for (int f = 0; f < 2; ++f) {
                const int col = f * 16 + fr;         // 0..31
#pragma unroll
                for (int r = 0; r < 4; ++r)
                    oS[(crow + r) * 33 + col] = apv[cf][2 * h + f][r];
            }
        }
        barrier_lgkm();                  // repack (+ agL at h=0) visible
#pragma unroll
        for (int p = 0; p < 8; ++p) {
            const int ch  = p * 512 + tid;
            const int row = ch >> 3;     // c
            const int sg  = ch & 7;
            const int ib  = h * 32 + sg * 4;   // i_local base
            f32x4 o = *(const f32x4*)&oS[row * 33 + sg * 4];
            const size_t idx = ((size_t)b * C + row) * N + i0 + ib;
            f32x4 xv = *(const f32x4*)&x[idx];
            f32x4 of, oa;
#pragma unroll
            for (int q = 0; q < 4; ++q) {
                of[q] = gmm * o[q] + xv[q];
                oa[q] = o[q] * (1.f - agL[ib + q]);
            }
            *(f32x4*)&dout[idx]       = of;
            *(f32x4*)&dout[BCN + idx] = oa;
        }
        barrier_lgkm();                  // LDS reads done before next h repack
    }
}

// ---------------------------------------------------------------------------
// Transpose x[b][c][n] fp32 -> xT[b][n][c] fp16, with prep_weights folded
// into the first 1024 wgs (removes one dispatch + gap).
// ---------------------------------------------------------------------------
__global__ void transpose_prep(const float* __restrict__ x,
                               ushort* __restrict__ xT,
                               const float* __restrict__ Wq,
                               const float* __restrict__ Wk,
                               const float* __restrict__ Wv,
                               const float* __restrict__ bq,
                               const float* __restrict__ bk,
                               ushort* __restrict__ Wqk,
                               ushort* __restrict__ Wv16,
                               float* __restrict__ bqk) {
    __shared__ float t[32][33];
    int tid = threadIdx.x;

    // prep slice (first 1024 wgs)
    const int linwg = blockIdx.x + 32 * (blockIdx.y + 16 * blockIdx.z);
    if (linwg < 1024) {
        int i = linwg * 256 + tid;
        if (i < CQ * C) {
            Wqk[i]          = f2h(Wq[i]);
            Wqk[CQ * C + i] = f2h(Wk[i]);
        }
        if (i < C * C) Wv16[i] = f2h(Wv[i]);
        if (i < 512) bqk[i] = (i < CQ) ? bq[i] : bk[i - CQ];
    }

    int b  = blockIdx.z;
    int c0 = blockIdx.y * 32;
    int n0 = blockIdx.x * 32;
    int tx = tid & 31;
    int ty = tid >> 5;
#pragma unroll
    for (int r = 0; r < 4; ++r)
        t[ty + r * 8][tx] = x[(size_t)b * C * N + (size_t)(c0 + ty + r * 8) * N + n0 + tx];
    __syncthreads();
#pragma unroll
    for (int r = 0; r < 4; ++r) {
        float v = t[tx][ty + r * 8];
        size_t idx = (size_t)b * N * C + (size_t)(n0 + ty + r * 8) * C + c0 + tx;
        xT[idx] = f2h(v);
    }
}

extern "C" void kernel_launch(void* const* d_in, const int* in_sizes, int n_in,
                              void* d_out, int out_size, void* d_ws, size_t ws_size,
                              hipStream_t stream) {
    const float* x     = (const float*)d_in[0];
    const float* Wq    = (const float*)d_in[1];
    const float* bq    = (const float*)d_in[2];
    const float* Wk    = (const float*)d_in[3];
    const float* bk    = (const float*)d_in[4];
    const float* Wv    = (const float*)d_in[5];
    const float* bv    = (const float*)d_in[6];
    const float* Wa    = (const float*)d_in[7];
    const float* ba    = (const float*)d_in[8];
    const float* gamma = (const float*)d_in[9];
    float* out = (float*)d_out;

    // Workspace (MiB offsets)
    const size_t MB = 1048576;
    char* ws = (char*)d_ws;
    ushort* v_     = (ushort*)(ws);                //  0..16  v [b][c][n] fp16
    ushort* qkT    = (ushort*)(ws + 16 * MB);      // 16..32  [b][n][512] fp16
    ushort* Wqk    = (ushort*)(ws + 48 * MB);      // 512 KB  [Wq;Wk] fp16
    ushort* Wv16   = (ushort*)(ws + 48 * MB + 524288);  // 512 KB fp16
    float*  bqk    = (float*)(ws + 49 * MB);       // 2 KB
    ushort* xT     = (ushort*)(ws + 80 * MB);      // 80..96  fp16 [b][n][c]
    const size_t need = 96 * MB;
    if (ws_size < need) return;

    dim3 blk(256);
    transpose_prep<<<dim3(N / 32, C / 32, B), blk, 0, stream>>>(
        x, xT, Wq, Wk, Wv, bq, bk, Wqk, Wv16, bqk);

    // Both projection GEMMs, one dispatch, per-half XCD mapping preserved
    gemm_merged<<<dim3(1024), blk, 0, stream>>>(
        xT, Wqk, Wv16, qkT, v_, bqk, bv);

    // fully fused QK^T + softmax + PV (counted-vmcnt) + gate + epilogue
    fused_attn<<<dim3(16, 16), dim3(512), 0, stream>>>(
        qkT, v_, Wa, ba, gamma, x, out);
}

// Round 7
// 124.409 us; speedup vs baseline: 1.0337x; 1.0337x over previous
//
#include <hip/hip_runtime.h>
#include <hip/hip_bf16.h>
#include <math.h>

#define B 16
#define C 512
#define CQ 256
#define N 1024

typedef short bf16x8 __attribute__((ext_vector_type(8)));
typedef _Float16 f16x8 __attribute__((ext_vector_type(8)));
typedef float f32x4 __attribute__((ext_vector_type(4)));
typedef unsigned short ushort;

__device__ __forceinline__ unsigned short f2bf(float f) {
    __hip_bfloat16 h = __float2bfloat16(f);
    return *(unsigned short*)&h;
}
__device__ __forceinline__ ushort f2h(float f) {
    _Float16 h = (_Float16)f;
    return *(ushort*)&h;
}
__device__ __forceinline__ f16x8 as_h(bf16x8 v) {
    union { bf16x8 s; f16x8 h; } u; u.s = v; return u.h;
}

__device__ __forceinline__ void gload16(void* lds, const void* g) {
    __builtin_amdgcn_global_load_lds(
        (const __attribute__((address_space(1))) void*)g,
        (__attribute__((address_space(3))) void*)lds, 16, 0, 0);
}

__device__ __forceinline__ void barrier_lgkm() {
    asm volatile("s_waitcnt lgkmcnt(0)" ::: "memory");
    __builtin_amdgcn_s_barrier();
    __builtin_amdgcn_sched_barrier(0);
}

// ---------------------------------------------------------------------------
// MFMA GEMM, BK=128, XOR-swizzled LDS. C[b][row][col] = sum_k A[b][row][k] *
// BT[b][col][k] (+bias). 128x128 tile, 256 thr = 4 waves (2x2). K % 128 == 0.
// OUT_MODE: 0 fp32, 1 bf16, 3 fp16. BIAS_MODE: 0 none, 1 row, 2 col.
// XSWZ: XCD remap (grid x*y==32, z==16). DT: 0 bf16 MFMA, 1 fp16 MFMA.
// (Merging the two GEMM dispatches regressed twice — r4: XCD mapping broken;
// r6: mapping preserved but concurrent halves thrash per-XCD L2. Keep split.)
// ---------------------------------------------------------------------------
template<int OUT_MODE, int BIAS_MODE, int XSWZ, int DT>
__global__ __launch_bounds__(256) void gemm128s(
    const ushort* __restrict__ A, long long sA,
    const ushort* __restrict__ BT, long long sB,
    void* __restrict__ Ch, long long sC,
    const float* __restrict__ bias, int K, int Ncols)
{
    __shared__ __align__(16) ushort As[128 * 128];   // 32 KB
    __shared__ __align__(16) ushort Bs[128 * 128];   // 32 KB

    int bx, by, bz;
    if constexpr (XSWZ) {
        const int lin  = blockIdx.x + gridDim.x * (blockIdx.y + gridDim.y * blockIdx.z);
        const int xcd  = lin & 7;
        const int slot = lin >> 3;          // 0..63
        bz = xcd + 8 * (slot >> 5);         // batch
        const int wxy = slot & 31;
        bx = wxy % gridDim.x;
        by = wxy / gridDim.x;
    } else {
        bx = blockIdx.x; by = blockIdx.y; bz = blockIdx.z;
    }

    const int tid  = threadIdx.x;
    const int lane = tid & 63;
    const int w    = tid >> 6;
    const int wr   = (w >> 1) * 64;
    const int wc   = (w & 1) * 64;
    const int fr   = lane & 15;
    const int ko2  = (lane >> 4) * 16;      // byte offset of lane's K-octet

    const int brow = by * 128;
    const int bcol = bx * 128;
    const size_t K2 = (size_t)K * 2;

    const char* Ab = (const char*)(A  + (size_t)bz * sA + (size_t)brow * K);
    const char* Bb = (const char*)(BT + (size_t)bz * sB + (size_t)bcol * K);

    const int sr = tid >> 4;            // staging row base 0..15
    const int ss = (tid & 15) * 16;     // byte seg within 256B row

    f32x4 acc[4][4] = {};

    for (int k0 = 0; k0 < K; k0 += 128) {
#pragma unroll
        for (int p = 0; p < 8; ++p) {
            const int row = p * 16 + sr;
            const size_t so = (size_t)row * K2 + (size_t)k0 * 2
                            + (size_t)(ss ^ ((row & 15) << 4));
            gload16((char*)As + p * 4096 + tid * 16, Ab + so);
            gload16((char*)Bs + p * 4096 + tid * 16, Bb + so);
        }
        __syncthreads();
#pragma unroll
        for (int k32 = 0; k32 < 4; ++k32) {
            const int kswz = (k32 * 64 + ko2) ^ (fr << 4);
            bf16x8 ah[4], bh[4];
#pragma unroll
            for (int m = 0; m < 4; ++m)
                ah[m] = *(const bf16x8*)((const char*)As + (wr + m * 16 + fr) * 256 + kswz);
#pragma unroll
            for (int n = 0; n < 4; ++n)
                bh[n] = *(const bf16x8*)((const char*)Bs + (wc + n * 16 + fr) * 256 + kswz);
            if constexpr (DT == 1) {
#pragma unroll
                for (int m = 0; m < 4; ++m)
#pragma unroll
                    for (int n = 0; n < 4; ++n)
                        acc[m][n] = __builtin_amdgcn_mfma_f32_16x16x32_f16(
                            as_h(ah[m]), as_h(bh[n]), acc[m][n], 0, 0, 0);
            } else {
#pragma unroll
                for (int m = 0; m < 4; ++m)
#pragma unroll
                    for (int n = 0; n < 4; ++n)
                        acc[m][n] = __builtin_amdgcn_mfma_f32_16x16x32_bf16(
                            ah[m], bh[n], acc[m][n], 0, 0, 0);
            }
        }
        __syncthreads();
    }

    // Epilogue: C/D layout col = lane&15, row = (lane>>4)*4 + r
    const int crow = brow + wr + (lane >> 4) * 4;
    const int ccol = bcol + wc + fr;
    const size_t cbase = (size_t)bz * sC;
#pragma unroll
    for (int m = 0; m < 4; ++m) {
#pragma unroll
        for (int n = 0; n < 4; ++n) {
            float cb = (BIAS_MODE == 2) ? bias[ccol + n * 16] : 0.f;
#pragma unroll
            for (int r = 0; r < 4; ++r) {
                int row = crow + m * 16 + r;
                int col = ccol + n * 16;
                float vv = acc[m][n][r];
                if (BIAS_MODE == 1) vv += bias[row];
                if (BIAS_MODE == 2) vv += cb;
                size_t idx = cbase + (size_t)row * Ncols + col;
                if (OUT_MODE == 0)      ((float*)Ch)[idx]  = vv;
                else if (OUT_MODE == 1) ((ushort*)Ch)[idx] = f2bf(vv);
                else                    ((ushort*)Ch)[idx] = f2h(vv);
            }
        }
    }
}

// ---------------------------------------------------------------------------
// Fully fused attention — round-0 structure with K and V DE-STAGED:
// K (1 MB/batch) + V (2 MB/batch) are L2-resident per XCD (<4 MB with Q),
// so LDS staging was pure overhead (m169 lesson): it forced
// s_waitcnt+s_barrier synchronized consumption 32x at only 2 waves/SIMD.
// Now:
//  - QK: b_h fragments read DIRECT from global (16 rows x 64 B gathers,
//    L2 hits). Zero LDS, ZERO barriers in the whole QK phase — compiler
//    software-pipelines 128 loads across 256 MFMAs per thread.
//    (K bytes read 2x per wg since row-groups share columns: +0.5 MB L2/wg.)
//  - PV: V fragments read direct from global; only the P repack (cross-wave)
//    uses LDS, double-buffered, ONE barrier_lgkm per jt. No vmcnt discipline.
// Operand bytes and accumulation order identical to round 0 => bitwise-same
// output (absmax 0.0390625).
// Occupancy note: 128 VGPR + 128 AGPR = 256 regs/wave pins 8 waves/CU (m69);
// LDS is irrelevant to occupancy here, so shrinking it is cosmetic.
// ---------------------------------------------------------------------------
__global__ __launch_bounds__(512, 2) void fused_attn(
    const ushort* __restrict__ qk, const ushort* __restrict__ vmat,
    const float* __restrict__ Wa, const float* __restrict__ ba,
    const float* __restrict__ gamma, const float* __restrict__ x,
    float* __restrict__ dout)
{
    __shared__ __align__(16) char lds[86016];   // oS repack 67584 | P 2x9216
    __shared__ float redbuf[2][2][4][32];
    __shared__ float redA[8][64];
    __shared__ float agL[64];

    const int tid  = threadIdx.x;
    const int lane = tid & 63;
    const int w    = tid >> 6;           // 0..7
    const int g    = w >> 2;             // QK row group 0/1
    const int wg4  = w & 3;              // QK col-wave within group
    const int fr   = lane & 15;
    const int il0  = (lane >> 4) * 4;
    const int ko2  = (lane >> 4) * 16;   // byte offset of lane's K-octet

    // XCD-aware bijective remap (256 wgs, 8 XCDs => 2 batches/XCD)
    const int wgid = blockIdx.x + gridDim.x * blockIdx.y;
    const int nid  = (wgid & 7) * 32 + (wgid >> 3);
    const int b    = nid >> 4;
    const int i0   = (nid & 15) * 64;

    const char* qkB = (const char*)qk + (size_t)b * N * 1024;
    const char* vB  = (const char*)vmat + (size_t)b * C * N * 2;

    // ---- hoist q fragments for BOTH K-halves (global -> VGPR) ----
    f16x8 a_h[2][2][4];
#pragma unroll
    for (int ks0 = 0; ks0 < 2; ++ks0)
#pragma unroll
        for (int m = 0; m < 2; ++m) {
            const char* qr = qkB + (size_t)(i0 + g * 32 + m * 16 + fr) * 1024
                           + ks0 * 256 + (lane >> 4) * 16;
#pragma unroll
            for (int k32 = 0; k32 < 4; ++k32)
                a_h[ks0][m][k32] = *(const f16x8*)(qr + k32 * 64);
        }

    f32x4 acc[16][2];
#pragma unroll
    for (int jt = 0; jt < 16; ++jt)
#pragma unroll
        for (int m = 0; m < 2; ++m)
            acc[jt][m] = (f32x4){0.f, 0.f, 0.f, 0.f};

    // ---- QK phase: direct-global K, no LDS, no barriers ----
#pragma unroll
    for (int s = 0; s < 16; ++s) {
        const int ks0 = s >> 3;
#pragma unroll
        for (int sub = 0; sub < 2; ++sub) {
            const int jrow = (s & 7) * 128 + sub * 64 + wg4 * 16 + fr;
            const int jidx = (s & 7) * 2 + sub;
            const char* kr = qkB + (size_t)jrow * 1024 + 512 + ks0 * 256;
#pragma unroll
            for (int k32 = 0; k32 < 4; ++k32) {
                f16x8 b_h = *(const f16x8*)(kr + k32 * 64 + ko2);
#pragma unroll
                for (int m = 0; m < 2; ++m)
                    acc[jidx][m] = __builtin_amdgcn_mfma_f32_16x16x32_f16(
                        a_h[ks0][m][k32], b_h, acc[jidx][m], 0, 0, 0);
            }
        }
    }

    // ---- row max ----
    float mx[2][4];
#pragma unroll
    for (int m = 0; m < 2; ++m)
#pragma unroll
        for (int r = 0; r < 4; ++r) {
            float v = acc[0][m][r];
#pragma unroll
            for (int jt = 1; jt < 16; ++jt) v = fmaxf(v, acc[jt][m][r]);
            mx[m][r] = v;
        }
#pragma unroll
    for (int off = 1; off < 16; off <<= 1)
#pragma unroll
        for (int m = 0; m < 2; ++m)
#pragma unroll
            for (int r = 0; r < 4; ++r)
                mx[m][r] = fmaxf(mx[m][r], __shfl_xor(mx[m][r], off, 64));
    if (fr == 0) {
#pragma unroll
        for (int m = 0; m < 2; ++m)
#pragma unroll
            for (int r = 0; r < 4; ++r)
                redbuf[0][g][wg4][m * 16 + il0 + r] = mx[m][r];
    }
    barrier_lgkm();
#pragma unroll
    for (int m = 0; m < 2; ++m)
#pragma unroll
        for (int r = 0; r < 4; ++r) {
            const int row = m * 16 + il0 + r;
            mx[m][r] = fmaxf(fmaxf(redbuf[0][g][0][row], redbuf[0][g][1][row]),
                             fmaxf(redbuf[0][g][2][row], redbuf[0][g][3][row]));
        }

    // ---- exp + row sum ----
    float sm[2][4] = {};
#pragma unroll
    for (int jt = 0; jt < 16; ++jt)
#pragma unroll
        for (int m = 0; m < 2; ++m) {
            f32x4 e;
#pragma unroll
            for (int r = 0; r < 4; ++r) {
                e[r] = __expf(acc[jt][m][r] - mx[m][r]);
                sm[m][r] += e[r];
            }
            acc[jt][m] = e;
        }
#pragma unroll
    for (int off = 1; off < 16; off <<= 1)
#pragma unroll
        for (int m = 0; m < 2; ++m)
#pragma unroll
            for (int r = 0; r < 4; ++r)
                sm[m][r] += __shfl_xor(sm[m][r], off, 64);
    if (fr == 0) {
#pragma unroll
        for (int m = 0; m < 2; ++m)
#pragma unroll
            for (int r = 0; r < 4; ++r)
                redbuf[1][g][wg4][m * 16 + il0 + r] = sm[m][r];
    }
    barrier_lgkm();
#pragma unroll
    for (int m = 0; m < 2; ++m)
#pragma unroll
        for (int r = 0; r < 4; ++r) {
            const int row = m * 16 + il0 + r;
            float s = redbuf[1][g][0][row] + redbuf[1][g][1][row]
                    + redbuf[1][g][2][row] + redbuf[1][g][3][row];
            mx[m][r] = 1.f / s;        // reuse mx as inv-sum
        }

    // ---- PV phase: direct-global V, LDS only for P (double-buffered) ----
    char* pPb = lds + 67584;             // 2 P buffers x 9216 B
    f32x4 apv[4][4] = {};                // [c-frag][i-frag]

#pragma unroll
    for (int jt = 0; jt < 16; ++jt) {
        ushort* pS = (ushort*)(pPb + (jt & 1) * 9216);
#pragma unroll
        for (int m = 0; m < 2; ++m) {
            const int lr = g * 32 + m * 16 + il0;
#pragma unroll
            for (int r = 0; r < 4; ++r)
                pS[(lr + r) * 72 + wg4 * 16 + fr] = f2h(acc[jt][m][r] * mx[m][r]);
        }
        barrier_lgkm();                  // P(jt) visible; prev reads drained
#pragma unroll
        for (int k32 = 0; k32 < 2; ++k32) {
            f16x8 af[4], bf[4];
#pragma unroll
            for (int cf = 0; cf < 4; ++cf) {
                const int row = w * 64 + cf * 16 + fr;
                af[cf] = *(const f16x8*)(vB + (size_t)row * 2048
                                         + jt * 128 + k32 * 64 + ko2);
            }
#pragma unroll
            for (int f = 0; f < 4; ++f)
                bf[f] = *(const f16x8*)((const char*)pS
                        + (f * 16 + fr) * 144 + k32 * 64 + ko2);
#pragma unroll
            for (int cf = 0; cf < 4; ++cf)
#pragma unroll
                for (int f = 0; f < 4; ++f)
                    apv[cf][f] = __builtin_amdgcn_mfma_f32_16x16x32_f16(
                        af[cf], bf[f], apv[cf][f], 0, 0, 0);
        }
    }

    // ---- gate ----
    float pg[4] = {0.f, 0.f, 0.f, 0.f};
#pragma unroll
    for (int cf = 0; cf < 4; ++cf)
#pragma unroll
        for (int r = 0; r < 4; ++r) {
            const float wv = Wa[w * 64 + cf * 16 + il0 + r];
#pragma unroll
            for (int f = 0; f < 4; ++f)
                pg[f] += wv * apv[cf][f][r];
        }
#pragma unroll
    for (int off = 16; off < 64; off <<= 1)
#pragma unroll
        for (int f = 0; f < 4; ++f)
            pg[f] += __shfl_xor(pg[f], off, 64);
    if (lane < 16) {
#pragma unroll
        for (int f = 0; f < 4; ++f)
            redA[w][f * 16 + fr] = pg[f];
    }
    barrier_lgkm();                      // P reads consumed; redA visible
    if (tid < 64) {
        float s = ba[0];
#pragma unroll
        for (int k = 0; k < 8; ++k) s += redA[k][tid];
        agL[tid] = 1.f / (1.f + __expf(-s));
    }

    // ---- final epilogue: per i-half, fp32 repack (pad 33 dwords) + store ----
    const size_t BCN = (size_t)B * C * N;
    const float gmm = gamma[0];
    float* oS = (float*)lds;             // 512 rows x 33 f32 = 67584 B

#pragma unroll
    for (int h = 0; h < 2; ++h) {
#pragma unroll
        for (int cf = 0; cf < 4; ++cf) {
            const int crow = w * 64 + cf * 16 + il0;
#pragma unroll
            for (int f = 0; f < 2; ++f) {
                const int col = f * 16 + fr;         // 0..31
#pragma unroll
                for (int r = 0; r < 4; ++r)
                    oS[(crow + r) * 33 + col] = apv[cf][2 * h + f][r];
            }
        }
        barrier_lgkm();                  // repack (+ agL at h=0) visible
#pragma unroll
        for (int p = 0; p < 8; ++p) {
            const int ch  = p * 512 + tid;
            const int row = ch >> 3;     // c
            const int sg  = ch & 7;
            const int ib  = h * 32 + sg * 4;   // i_local base
            f32x4 o = *(const f32x4*)&oS[row * 33 + sg * 4];
            const size_t idx = ((size_t)b * C + row) * N + i0 + ib;
            f32x4 xv = *(const f32x4*)&x[idx];
            f32x4 of, oa;
#pragma unroll
            for (int q = 0; q < 4; ++q) {
                of[q] = gmm * o[q] + xv[q];
                oa[q] = o[q] * (1.f - agL[ib + q]);
            }
            *(f32x4*)&dout[idx]       = of;
            *(f32x4*)&dout[BCN + idx] = oa;
        }
        barrier_lgkm();                  // LDS reads done before next h repack
    }
}

// ---------------------------------------------------------------------------
// Transpose: x[b][c][n] fp32 -> xT[b][n][c] fp16
// ---------------------------------------------------------------------------
__global__ void transpose_x_f16(const float* __restrict__ x,
                                ushort* __restrict__ xT) {
    __shared__ float t[32][33];
    int b  = blockIdx.z;
    int c0 = blockIdx.y * 32;
    int n0 = blockIdx.x * 32;
    int tid = threadIdx.x;
    int tx = tid & 31;
    int ty = tid >> 5;
#pragma unroll
    for (int r = 0; r < 4; ++r)
        t[ty + r * 8][tx] = x[(size_t)b * C * N + (size_t)(c0 + ty + r * 8) * N + n0 + tx];
    __syncthreads();
#pragma unroll
    for (int r = 0; r < 4; ++r) {
        float v = t[tx][ty + r * 8];
        size_t idx = (size_t)b * N * C + (size_t)(n0 + ty + r * 8) * C + c0 + tx;
        xT[idx] = f2h(v);
    }
}

// ---------------------------------------------------------------------------
// Merged weight prep (full fp16): [Wq;Wk] fp16, Wv fp16, bias concat.
// ---------------------------------------------------------------------------
__global__ void prep_weights(const float* __restrict__ Wq, const float* __restrict__ Wk,
                             const float* __restrict__ Wv,
                             const float* __restrict__ bq, const float* __restrict__ bk,
                             ushort* __restrict__ Wqk, ushort* __restrict__ Wv16,
                             float* __restrict__ bqk) {
    int i = blockIdx.x * 256 + threadIdx.x;
    if (i < CQ * C) {
        Wqk[i]          = f2h(Wq[i]);
        Wqk[CQ * C + i] = f2h(Wk[i]);
    }
    if (i < C * C) Wv16[i] = f2h(Wv[i]);
    if (i < 512) bqk[i] = (i < CQ) ? bq[i] : bk[i - CQ];
}

extern "C" void kernel_launch(void* const* d_in, const int* in_sizes, int n_in,
                              void* d_out, int out_size, void* d_ws, size_t ws_size,
                              hipStream_t stream) {
    const float* x     = (const float*)d_in[0];
    const float* Wq    = (const float*)d_in[1];
    const float* bq    = (const float*)d_in[2];
    const float* Wk    = (const float*)d_in[3];
    const float* bk    = (const float*)d_in[4];
    const float* Wv    = (const float*)d_in[5];
    const float* bv    = (const float*)d_in[6];
    const float* Wa    = (const float*)d_in[7];
    const float* ba    = (const float*)d_in[8];
    const float* gamma = (const float*)d_in[9];
    float* out = (float*)d_out;

    // Workspace (MiB offsets)
    const size_t MB = 1048576;
    char* ws = (char*)d_ws;
    ushort* v_     = (ushort*)(ws);                //  0..16  v [b][c][n] fp16
    ushort* qkT    = (ushort*)(ws + 16 * MB);      // 16..32  [b][n][512] fp16
    ushort* Wqk    = (ushort*)(ws + 48 * MB);      // 512 KB  [Wq;Wk] fp16
    ushort* Wv16   = (ushort*)(ws + 48 * MB + 524288);  // 512 KB fp16
    float*  bqk    = (float*)(ws + 49 * MB);       // 2 KB
    ushort* xT     = (ushort*)(ws + 80 * MB);      // 80..96  fp16 [b][n][c]
    const size_t need = 96 * MB;
    if (ws_size < need) return;

    dim3 blk(256);
    transpose_x_f16<<<dim3(N / 32, C / 32, B), blk, 0, stream>>>(x, xT);
    prep_weights<<<dim3(C * C / 256), blk, 0, stream>>>(
        Wq, Wk, Wv, bq, bk, Wqk, Wv16, bqk);

    // qkT[b][n][0..511] = xT[b] . [Wq;Wk]^T + bqk[col]  (fp16 in/out, BK=128)
    gemm128s<3, 2, 1, 1><<<dim3(4, 8, B), blk, 0, stream>>>(
        xT, (long long)N * C, Wqk, 0,
        qkT, (long long)N * 512, bqk, C, 512);
    // v[b][c][n] = Wv . xT[b]^T + bv[row]    (fp16 in/out)
    gemm128s<3, 1, 1, 1><<<dim3(8, 4, B), blk, 0, stream>>>(
        Wv16, 0, xT, (long long)N * C,
        v_, (long long)C * N, bv, C, N);
    // fused QK^T (direct-K) + softmax + PV (direct-V) + gate + epilogue
    fused_attn<<<dim3(16, 16), dim3(512), 0, stream>>>(
        qkT, v_, Wa, ba, gamma, x, out);
}

// Round 8
// 95.870 us; speedup vs baseline: 1.3415x; 1.2977x over previous
//
#include <hip/hip_runtime.h>
#include <hip/hip_bf16.h>
#include <math.h>

#define B 16
#define C 512
#define CQ 256
#define N 1024

typedef short bf16x8 __attribute__((ext_vector_type(8)));
typedef _Float16 f16x8 __attribute__((ext_vector_type(8)));
typedef float f32x4 __attribute__((ext_vector_type(4)));
typedef unsigned short ushort;

__device__ __forceinline__ unsigned short f2bf(float f) {
    __hip_bfloat16 h = __float2bfloat16(f);
    return *(unsigned short*)&h;
}
__device__ __forceinline__ ushort f2h(float f) {
    _Float16 h = (_Float16)f;
    return *(ushort*)&h;
}
__device__ __forceinline__ f16x8 as_h(bf16x8 v) {
    union { bf16x8 s; f16x8 h; } u; u.s = v; return u.h;
}

__device__ __forceinline__ void gload16(void* lds, const void* g) {
    __builtin_amdgcn_global_load_lds(
        (const __attribute__((address_space(1))) void*)g,
        (__attribute__((address_space(3))) void*)lds, 16, 0, 0);
}

__device__ __forceinline__ void barrier_lgkm() {
    asm volatile("s_waitcnt lgkmcnt(0)" ::: "memory");
    __builtin_amdgcn_s_barrier();
    __builtin_amdgcn_sched_barrier(0);
}

// ---------------------------------------------------------------------------
// MFMA GEMM, BK=128, XOR-swizzled LDS. C[b][row][col] = sum_k A[b][row][k] *
// BT[b][col][k] (+bias). 128x128 tile, 256 thr = 4 waves (2x2). K % 128 == 0.
// OUT_MODE: 0 fp32, 1 bf16, 3 fp16. BIAS_MODE: 0 none, 1 row, 2 col.
// XSWZ: XCD remap (grid x*y==32, z==16). DT: 0 bf16 MFMA, 1 fp16 MFMA.
// Session ledger: keep SPLIT dispatches (merge regressed twice: r4 broke the
// XCD bit; r6 preserved it but concurrent halves thrash per-XCD L2).
// ---------------------------------------------------------------------------
template<int OUT_MODE, int BIAS_MODE, int XSWZ, int DT>
__global__ __launch_bounds__(256) void gemm128s(
    const ushort* __restrict__ A, long long sA,
    const ushort* __restrict__ BT, long long sB,
    void* __restrict__ Ch, long long sC,
    const float* __restrict__ bias, int K, int Ncols)
{
    __shared__ __align__(16) ushort As[128 * 128];   // 32 KB
    __shared__ __align__(16) ushort Bs[128 * 128];   // 32 KB

    int bx, by, bz;
    if constexpr (XSWZ) {
        const int lin  = blockIdx.x + gridDim.x * (blockIdx.y + gridDim.y * blockIdx.z);
        const int xcd  = lin & 7;
        const int slot = lin >> 3;          // 0..63
        bz = xcd + 8 * (slot >> 5);         // batch
        const int wxy = slot & 31;
        bx = wxy % gridDim.x;
        by = wxy / gridDim.x;
    } else {
        bx = blockIdx.x; by = blockIdx.y; bz = blockIdx.z;
    }

    const int tid  = threadIdx.x;
    const int lane = tid & 63;
    const int w    = tid >> 6;
    const int wr   = (w >> 1) * 64;
    const int wc   = (w & 1) * 64;
    const int fr   = lane & 15;
    const int ko2  = (lane >> 4) * 16;      // byte offset of lane's K-octet

    const int brow = by * 128;
    const int bcol = bx * 128;
    const size_t K2 = (size_t)K * 2;

    const char* Ab = (const char*)(A  + (size_t)bz * sA + (size_t)brow * K);
    const char* Bb = (const char*)(BT + (size_t)bz * sB + (size_t)bcol * K);

    const int sr = tid >> 4;            // staging row base 0..15
    const int ss = (tid & 15) * 16;     // byte seg within 256B row

    f32x4 acc[4][4] = {};

    for (int k0 = 0; k0 < K; k0 += 128) {
#pragma unroll
        for (int p = 0; p < 8; ++p) {
            const int row = p * 16 + sr;
            const size_t so = (size_t)row * K2 + (size_t)k0 * 2
                            + (size_t)(ss ^ ((row & 15) << 4));
            gload16((char*)As + p * 4096 + tid * 16, Ab + so);
            gload16((char*)Bs + p * 4096 + tid * 16, Bb + so);
        }
        __syncthreads();
#pragma unroll
        for (int k32 = 0; k32 < 4; ++k32) {
            const int kswz = (k32 * 64 + ko2) ^ (fr << 4);
            bf16x8 ah[4], bh[4];
#pragma unroll
            for (int m = 0; m < 4; ++m)
                ah[m] = *(const bf16x8*)((const char*)As + (wr + m * 16 + fr) * 256 + kswz);
#pragma unroll
            for (int n = 0; n < 4; ++n)
                bh[n] = *(const bf16x8*)((const char*)Bs + (wc + n * 16 + fr) * 256 + kswz);
            if constexpr (DT == 1) {
#pragma unroll
                for (int m = 0; m < 4; ++m)
#pragma unroll
                    for (int n = 0; n < 4; ++n)
                        acc[m][n] = __builtin_amdgcn_mfma_f32_16x16x32_f16(
                            as_h(ah[m]), as_h(bh[n]), acc[m][n], 0, 0, 0);
            } else {
#pragma unroll
                for (int m = 0; m < 4; ++m)
#pragma unroll
                    for (int n = 0; n < 4; ++n)
                        acc[m][n] = __builtin_amdgcn_mfma_f32_16x16x32_bf16(
                            ah[m], bh[n], acc[m][n], 0, 0, 0);
            }
        }
        __syncthreads();
    }

    // Epilogue: C/D layout col = lane&15, row = (lane>>4)*4 + r
    const int crow = brow + wr + (lane >> 4) * 4;
    const int ccol = bcol + wc + fr;
    const size_t cbase = (size_t)bz * sC;
#pragma unroll
    for (int m = 0; m < 4; ++m) {
#pragma unroll
        for (int n = 0; n < 4; ++n) {
            float cb = (BIAS_MODE == 2) ? bias[ccol + n * 16] : 0.f;
#pragma unroll
            for (int r = 0; r < 4; ++r) {
                int row = crow + m * 16 + r;
                int col = ccol + n * 16;
                float vv = acc[m][n][r];
                if (BIAS_MODE == 1) vv += bias[row];
                if (BIAS_MODE == 2) vv += cb;
                size_t idx = cbase + (size_t)row * Ncols + col;
                if (OUT_MODE == 0)      ((float*)Ch)[idx]  = vv;
                else if (OUT_MODE == 1) ((ushort*)Ch)[idx] = f2bf(vv);
                else                    ((ushort*)Ch)[idx] = f2h(vv);
            }
        }
    }
}

// ---------------------------------------------------------------------------
// Fully fused attention — the round-0 proven optimum, restored verbatim.
// Session ledger (8 rounds of A/B evidence) for why each piece stands:
//  - 512 thr, 2 waves/SIMD: LDS (146 KB) and regs (128 VGPR + 128 AGPR acc =
//    256/wave) are BOTH exactly at the 1-wg/CU point. 1024-thr variants force
//    a 128-reg budget and spill ~55 MB/dispatch (r1-r3).
//  - LDS staging for K and V: direct-global reads are 16-line gathers and
//    lose the LDS broadcast amortization (r7: +27 us).
//  - PV vmcnt(0)-per-jt: optimal for 2 V buffers; a counted wait needs a 3rd
//    64 KB buffer that doesn't fit (r6: KVBLK=32 4-buffer variant +17 us).
//  - Fused epilogue: only ~6 us marginal in-kernel; separate pass costs ~18
//    (r5: +11 us). setprio / x-prefetch: null (r4).
// QK: 4-buffer depth-2 counted-vmcnt {stageK(s+2); vmcnt(8); barrier; MFMA}.
// Softmax: lgkm-only barriers (stageV(0) stays in flight underneath).
// PV: {repack P; vmcnt(0)+lgkm; barrier; stageV(jt+1); MFMA(jt)}.
// Epilogue: fp32 repack (pad-33) + x read + dual store; lgkm-only barriers.
// ---------------------------------------------------------------------------
__global__ __launch_bounds__(512, 2) void fused_attn(
    const ushort* __restrict__ qk, const ushort* __restrict__ vmat,
    const float* __restrict__ Wa, const float* __restrict__ ba,
    const float* __restrict__ gamma, const float* __restrict__ x,
    float* __restrict__ dout)
{
    __shared__ __align__(16) char lds[149504];
    __shared__ float redbuf[2][2][4][32];
    __shared__ float redA[8][64];
    __shared__ float agL[64];

    const int tid  = threadIdx.x;
    const int lane = tid & 63;
    const int w    = tid >> 6;           // 0..7
    const int g    = w >> 2;             // QK row group 0/1
    const int wg4  = w & 3;              // QK col-wave within group
    const int fr   = lane & 15;
    const int il0  = (lane >> 4) * 4;
    const int ko2  = (lane >> 4) * 16;   // byte offset of lane's K-octet

    // XCD-aware bijective remap (256 wgs, 8 XCDs => 2 batches/XCD)
    const int wgid = blockIdx.x + gridDim.x * blockIdx.y;
    const int nid  = (wgid & 7) * 32 + (wgid >> 3);
    const int b    = nid >> 4;
    const int i0   = (nid & 15) * 64;

    const char* qkB = (const char*)qk + (size_t)b * N * 1024;
    const char* vB  = (const char*)vmat + (size_t)b * C * N * 2;

    const int srow = tid >> 4;          // 0..31
    const int ssg  = (tid & 15) * 16;   // byte seg in 256B row

    // ---- hoist q fragments for BOTH K-halves (global -> VGPR) ----
    f16x8 a_h[2][2][4];
#pragma unroll
    for (int ks0 = 0; ks0 < 2; ++ks0)
#pragma unroll
        for (int m = 0; m < 2; ++m) {
            const char* qr = qkB + (size_t)(i0 + g * 32 + m * 16 + fr) * 1024
                           + ks0 * 256 + (lane >> 4) * 16;
#pragma unroll
            for (int k32 = 0; k32 < 4; ++k32)
                a_h[ks0][m][k32] = *(const f16x8*)(qr + k32 * 64);
        }

    // ---- QK staging: 4 buffers of 32 KB ----
    auto stageK = [&](int s) {
        const int jt_  = s & 7;
        const int ks0_ = s >> 3;
        char* dst = lds + (s & 3) * 32768;
#pragma unroll
        for (int p = 0; p < 4; ++p) {
            const int row = p * 32 + srow;
            const size_t so = (size_t)(jt_ * 128 + row) * 1024 + 512
                            + (size_t)(ks0_ * 256)
                            + (size_t)(ssg ^ ((row & 15) << 4));
            gload16(dst + p * 8192 + tid * 16, qkB + so);
        }
    };

    f32x4 acc[16][2];
#pragma unroll
    for (int jt = 0; jt < 16; ++jt)
#pragma unroll
        for (int m = 0; m < 2; ++m)
            acc[jt][m] = (f32x4){0.f, 0.f, 0.f, 0.f};

    stageK(0);
    stageK(1);

#pragma unroll
    for (int s = 0; s < 16; ++s) {
        if (s + 2 < 16) stageK(s + 2);
        if (s < 14)       asm volatile("s_waitcnt vmcnt(8)" ::: "memory");
        else if (s == 14) asm volatile("s_waitcnt vmcnt(4)" ::: "memory");
        else              asm volatile("s_waitcnt vmcnt(0)" ::: "memory");
        __builtin_amdgcn_s_barrier();
        __builtin_amdgcn_sched_barrier(0);
        const char* kb = lds + (s & 3) * 32768;
        const int ks0 = s >> 3;
#pragma unroll
        for (int sub = 0; sub < 2; ++sub) {
            const int jrow = sub * 64 + wg4 * 16 + fr;   // 0..127
            const int rb   = jrow * 256;
            const int jidx = (s & 7) * 2 + sub;
#pragma unroll
            for (int k32 = 0; k32 < 4; ++k32) {
                const int kswz = (k32 * 64 + ko2) ^ (fr << 4);
                f16x8 b_h = *(const f16x8*)(kb + rb + kswz);
#pragma unroll
                for (int m = 0; m < 2; ++m)
                    acc[jidx][m] = __builtin_amdgcn_mfma_f32_16x16x32_f16(
                        a_h[ks0][m][k32], b_h, acc[jidx][m], 0, 0, 0);
            }
        }
    }

    // ---- V staging (2 x 64 KB) ----
    auto stageV = [&](int j) {
        char* dst = lds + (j & 1) * 65536;
#pragma unroll
        for (int p = 0; p < 8; ++p) {
            const int ch = p * 512 + tid;
            const int row = ch >> 3;
            const int sg  = (ch & 7) * 16;
            const size_t so = (size_t)row * (N * 2) + (size_t)(j * 128)
                            + (size_t)(sg ^ ((row & 7) << 4));
            gload16(dst + ch * 16, vB + so);
        }
    };
    stageV(0);                           // in flight under softmax

    // ---- row max (lgkm-only barriers; vmcnt untouched) ----
    float mx[2][4];
#pragma unroll
    for (int m = 0; m < 2; ++m)
#pragma unroll
        for (int r = 0; r < 4; ++r) {
            float v = acc[0][m][r];
#pragma unroll
            for (int jt = 1; jt < 16; ++jt) v = fmaxf(v, acc[jt][m][r]);
            mx[m][r] = v;
        }
#pragma unroll
    for (int off = 1; off < 16; off <<= 1)
#pragma unroll
        for (int m = 0; m < 2; ++m)
#pragma unroll
            for (int r = 0; r < 4; ++r)
                mx[m][r] = fmaxf(mx[m][r], __shfl_xor(mx[m][r], off, 64));
    if (fr == 0) {
#pragma unroll
        for (int m = 0; m < 2; ++m)
#pragma unroll
            for (int r = 0; r < 4; ++r)
                redbuf[0][g][wg4][m * 16 + il0 + r] = mx[m][r];
    }
    barrier_lgkm();
#pragma unroll
    for (int m = 0; m < 2; ++m)
#pragma unroll
        for (int r = 0; r < 4; ++r) {
            const int row = m * 16 + il0 + r;
            mx[m][r] = fmaxf(fmaxf(redbuf[0][g][0][row], redbuf[0][g][1][row]),
                             fmaxf(redbuf[0][g][2][row], redbuf[0][g][3][row]));
        }

    // ---- exp + row sum ----
    float sm[2][4] = {};
#pragma unroll
    for (int jt = 0; jt < 16; ++jt)
#pragma unroll
        for (int m = 0; m < 2; ++m) {
            f32x4 e;
#pragma unroll
            for (int r = 0; r < 4; ++r) {
                e[r] = __expf(acc[jt][m][r] - mx[m][r]);
                sm[m][r] += e[r];
            }
            acc[jt][m] = e;
        }
#pragma unroll
    for (int off = 1; off < 16; off <<= 1)
#pragma unroll
        for (int m = 0; m < 2; ++m)
#pragma unroll
            for (int r = 0; r < 4; ++r)
                sm[m][r] += __shfl_xor(sm[m][r], off, 64);
    if (fr == 0) {
#pragma unroll
        for (int m = 0; m < 2; ++m)
#pragma unroll
            for (int r = 0; r < 4; ++r)
                redbuf[1][g][wg4][m * 16 + il0 + r] = sm[m][r];
    }
    barrier_lgkm();
#pragma unroll
    for (int m = 0; m < 2; ++m)
#pragma unroll
        for (int r = 0; r < 4; ++r) {
            const int row = m * 16 + il0 + r;
            float s = redbuf[1][g][0][row] + redbuf[1][g][1][row]
                    + redbuf[1][g][2][row] + redbuf[1][g][3][row];
            mx[m][r] = 1.f / s;        // reuse mx as inv-sum
        }

    // ---- PV phase ----
    char* pPb = lds + 131072;
    f32x4 apv[4][4] = {};   // [c-frag][i-frag]

#pragma unroll
    for (int jt = 0; jt < 16; ++jt) {
        ushort* pS = (ushort*)(pPb + (jt & 1) * 9216);
#pragma unroll
        for (int m = 0; m < 2; ++m) {
            const int lr = g * 32 + m * 16 + il0;
#pragma unroll
            for (int r = 0; r < 4; ++r)
                pS[(lr + r) * 72 + wg4 * 16 + fr] = f2h(acc[jt][m][r] * mx[m][r]);
        }
        asm volatile("s_waitcnt vmcnt(0) lgkmcnt(0)" ::: "memory");
        __builtin_amdgcn_s_barrier();
        __builtin_amdgcn_sched_barrier(0);
        if (jt + 1 < 16) stageV(jt + 1); // overlaps MFMA(jt) + next repack
        const char* vb = lds + (jt & 1) * 65536;
#pragma unroll
        for (int k32 = 0; k32 < 2; ++k32) {
            f16x8 af[4], bf[4];
#pragma unroll
            for (int cf = 0; cf < 4; ++cf) {
                const int row = w * 64 + cf * 16 + fr;
                const int kb  = (k32 * 64 + ko2) ^ ((fr & 7) << 4);
                af[cf] = *(const f16x8*)(vb + row * 128 + kb);
            }
#pragma unroll
            for (int f = 0; f < 4; ++f)
                bf[f] = *(const f16x8*)((const char*)pS
                        + (f * 16 + fr) * 144 + k32 * 64 + ko2);
#pragma unroll
            for (int cf = 0; cf < 4; ++cf)
#pragma unroll
                for (int f = 0; f < 4; ++f)
                    apv[cf][f] = __builtin_amdgcn_mfma_f32_16x16x32_f16(
                        af[cf], bf[f], apv[cf][f], 0, 0, 0);
        }
    }

    // ---- gate ----
    float pg[4] = {0.f, 0.f, 0.f, 0.f};
#pragma unroll
    for (int cf = 0; cf < 4; ++cf)
#pragma unroll
        for (int r = 0; r < 4; ++r) {
            const float wv = Wa[w * 64 + cf * 16 + il0 + r];
#pragma unroll
            for (int f = 0; f < 4; ++f)
                pg[f] += wv * apv[cf][f][r];
        }
#pragma unroll
    for (int off = 16; off < 64; off <<= 1)
#pragma unroll
        for (int f = 0; f < 4; ++f)
            pg[f] += __shfl_xor(pg[f], off, 64);
    if (lane < 16) {
#pragma unroll
        for (int f = 0; f < 4; ++f)
            redA[w][f * 16 + fr] = pg[f];
    }
    barrier_lgkm();                      // V reads consumed; redA visible
    if (tid < 64) {
        float s = ba[0];
#pragma unroll
        for (int k = 0; k < 8; ++k) s += redA[k][tid];
        agL[tid] = 1.f / (1.f + __expf(-s));
    }

    // ---- final epilogue: per i-half, fp32 repack (pad 33 dwords) + store ----
    const size_t BCN = (size_t)B * C * N;
    const float gmm = gamma[0];
    float* oS = (float*)lds;             // 512 rows x 33 f32 = 67584 B

#pragma unroll
    for (int h = 0; h < 2; ++h) {
#pragma unroll
        for (int cf = 0; cf < 4; ++cf) {
            const int crow = w * 64 + cf * 16 + il0;
#pragma unroll
            for (int f = 0; f < 2; ++f) {
                const int col = f * 16 + fr;         // 0..31
#pragma unroll
                for (int r = 0; r < 4; ++r)
                    oS[(crow + r) * 33 + col] = apv[cf][2 * h + f][r];
            }
        }
        barrier_lgkm();                  // repack (+ agL at h=0) visible
#pragma unroll
        for (int p = 0; p < 8; ++p) {
            const int ch  = p * 512 + tid;
            const int row = ch >> 3;     // c
            const int sg  = ch & 7;
            const int ib  = h * 32 + sg * 4;   // i_local base
            f32x4 o = *(const f32x4*)&oS[row * 33 + sg * 4];
            const size_t idx = ((size_t)b * C + row) * N + i0 + ib;
            f32x4 xv = *(const f32x4*)&x[idx];
            f32x4 of, oa;
#pragma unroll
            for (int q = 0; q < 4; ++q) {
                of[q] = gmm * o[q] + xv[q];
                oa[q] = o[q] * (1.f - agL[ib + q]);
            }
            *(f32x4*)&dout[idx]       = of;
            *(f32x4*)&dout[BCN + idx] = oa;
        }
        barrier_lgkm();                  // LDS reads done before next h repack
    }
}

// ---------------------------------------------------------------------------
// Transpose x[b][c][n] fp32 -> xT[b][n][c] fp16, with prep_weights folded
// into the first 1024 wgs (the one r6 component the ledger isolates as
// positive, ~-2 us: removes a dispatch + gap; zero structural risk).
// ---------------------------------------------------------------------------
__global__ void transpose_prep(const float* __restrict__ x,
                               ushort* __restrict__ xT,
                               const float* __restrict__ Wq,
                               const float* __restrict__ Wk,
                               const float* __restrict__ Wv,
                               const float* __restrict__ bq,
                               const float* __restrict__ bk,
                               ushort* __restrict__ Wqk,
                               ushort* __restrict__ Wv16,
                               float* __restrict__ bqk) {
    __shared__ float t[32][33];
    int tid = threadIdx.x;

    // prep slice (first 1024 wgs cover C*C = 1024*256 elements)
    const int linwg = blockIdx.x + 32 * (blockIdx.y + 16 * blockIdx.z);
    if (linwg < 1024) {
        int i = linwg * 256 + tid;
        if (i < CQ * C) {
            Wqk[i]          = f2h(Wq[i]);
            Wqk[CQ * C + i] = f2h(Wk[i]);
        }
        if (i < C * C) Wv16[i] = f2h(Wv[i]);
        if (i < 512) bqk[i] = (i < CQ) ? bq[i] : bk[i - CQ];
    }

    int b  = blockIdx.z;
    int c0 = blockIdx.y * 32;
    int n0 = blockIdx.x * 32;
    int tx = tid & 31;
    int ty = tid >> 5;
#pragma unroll
    for (int r = 0; r < 4; ++r)
        t[ty + r * 8][tx] = x[(size_t)b * C * N + (size_t)(c0 + ty + r * 8) * N + n0 + tx];
    __syncthreads();
#pragma unroll
    for (int r = 0; r < 4; ++r) {
        float v = t[tx][ty + r * 8];
        size_t idx = (size_t)b * N * C + (size_t)(n0 + ty + r * 8) * C + c0 + tx;
        xT[idx] = f2h(v);
    }
}

extern "C" void kernel_launch(void* const* d_in, const int* in_sizes, int n_in,
                              void* d_out, int out_size, void* d_ws, size_t ws_size,
                              hipStream_t stream) {
    const float* x     = (const float*)d_in[0];
    const float* Wq    = (const float*)d_in[1];
    const float* bq    = (const float*)d_in[2];
    const float* Wk    = (const float*)d_in[3];
    const float* bk    = (const float*)d_in[4];
    const float* Wv    = (const float*)d_in[5];
    const float* bv    = (const float*)d_in[6];
    const float* Wa    = (const float*)d_in[7];
    const float* ba    = (const float*)d_in[8];
    const float* gamma = (const float*)d_in[9];
    float* out = (float*)d_out;

    // Workspace (MiB offsets)
    const size_t MB = 1048576;
    char* ws = (char*)d_ws;
    ushort* v_     = (ushort*)(ws);                //  0..16  v [b][c][n] fp16
    ushort* qkT    = (ushort*)(ws + 16 * MB);      // 16..32  [b][n][512] fp16
    ushort* Wqk    = (ushort*)(ws + 48 * MB);      // 512 KB  [Wq;Wk] fp16
    ushort* Wv16   = (ushort*)(ws + 48 * MB + 524288);  // 512 KB fp16
    float*  bqk    = (float*)(ws + 49 * MB);       // 2 KB
    ushort* xT     = (ushort*)(ws + 80 * MB);      // 80..96  fp16 [b][n][c]
    const size_t need = 96 * MB;
    if (ws_size < need) return;

    dim3 blk(256);
    transpose_prep<<<dim3(N / 32, C / 32, B), blk, 0, stream>>>(
        x, xT, Wq, Wk, Wv, bq, bk, Wqk, Wv16, bqk);

    // qkT[b][n][0..511] = xT[b] . [Wq;Wk]^T + bqk[col]  (fp16 in/out, BK=128)
    gemm128s<3, 2, 1, 1><<<dim3(4, 8, B), blk, 0, stream>>>(
        xT, (long long)N * C, Wqk, 0,
        qkT, (long long)N * 512, bqk, C, 512);
    // v[b][c][n] = Wv . xT[b]^T + bv[row]    (fp16 in/out)
    gemm128s<3, 1, 1, 1><<<dim3(8, 4, B), blk, 0, stream>>>(
        Wv16, 0, xT, (long long)N * C,
        v_, (long long)C * N, bv, C, N);
    // fully fused QK^T + softmax + PV + gate + epilogue -> dout
    fused_attn<<<dim3(16, 16), dim3(512), 0, stream>>>(
        qkT, v_, Wa, ba, gamma, x, out);
}